// Round 16
// baseline (158.674 us; speedup 1.0000x reference)
//
#include <hip/hip_runtime.h>

// ParticleI2cCell — R16 DIAGNOSTIC ROUND.
// Eight structural theories in a row were falsified while the hot kernel's
// counters were invisible (the harness's 268MB ws-poison fills at ~40us own
// all top-5 rocprof slots; our kernel runs ~24us). This round repeats the
// identical j-sweep REP=8x with asm-volatile opacity (rule #17: opaque
// zero-init per rep + sinks, unroll-1 rep loop) so the kernel runs ~195us,
// tops the profile, and yields VALUBusy / VGPR / Occupancy / FETCH for the
// real hot loop. Output = last rep's accumulators == R13 exactly (absmax 0).
// Decision rule for R17: VALUBusy>70% => issue-bound at degraded effective
// rate -> MFMA instruction-count rewrite; VALUBusy~25-35% => stall-bound
// with cached feed -> dependency/ILP restructure.

constexpr float LOG2E = 1.4426950408889634f;
constexpr float LN2   = 0.6931471805599453f;

// ---------------- single fused kernel, REP-repeated sweep ------------------
// grid = P/TR = 1024 blocks of 256 -> 4 blocks/CU, 16 waves/CU.
template <int TR, int BLOCK, int REP>
__global__ __launch_bounds__(BLOCK, 4) void fused_diag(
    const float* __restrict__ particles,   // [P][6]
    const float* __restrict__ samples,     // [P][4]
    const float* __restrict__ weights,     // [P]
    const float* __restrict__ log_weights, // [P]
    const float* __restrict__ A,           // [4][4]
    const float* __restrict__ B,           // [4][2]
    const float* __restrict__ log_sigma,   // [4]
    float* __restrict__ out, int P)
{
    constexpr int NW = BLOCK / 64;

    const int tid  = threadIdx.x;
    const int lane = tid & 63;
    const int wv   = tid >> 6;
    const int rowBase = blockIdx.x * TR;

    // ---- per-block uniform setup (outside the rep loop) ----
    float inv2[4], Kinv[4];
#pragma unroll
    for (int k = 0; k < 4; ++k) {
        float iv = __builtin_amdgcn_exp2f(-log_sigma[k] * LOG2E);
        inv2[k] = iv * iv;
        Kinv[k] = -0.5f * LOG2E * inv2[k];
    }

    float M0[TR], M1[TR], M2[TR], M3[TR];
#pragma unroll
    for (int r = 0; r < TR; ++r) {
        const float* pr = particles + (size_t)(rowBase + r) * 6;
        float x0 = pr[0], x1 = pr[1], x2 = pr[2], x3 = pr[3];
        float u0 = pr[4], u1 = pr[5];
        float mk[4];
#pragma unroll
        for (int k = 0; k < 4; ++k) {
            float mean =       A[k*4+0] * x0;
            mean = fmaf(A[k*4+1], x1, mean);
            mean = fmaf(A[k*4+2], x2, mean);
            mean = fmaf(A[k*4+3], x3, mean);
            mean = fmaf(B[k*2+0], u0, mean);
            mean = fmaf(B[k*2+1], u1, mean);
            mk[k] = mean;
        }
        M0[r] = LOG2E * mk[0] * inv2[0];
        M1[r] = LOG2E * mk[1] * inv2[1];
        M2[r] = LOG2E * mk[2] * inv2[2];
        M3[r] = LOG2E * mk[3] * inv2[3];
    }

    const float4* sf = reinterpret_cast<const float4*>(samples);
    const int iters = P / BLOCK;     // 32 at P=8192

    // opaque 0 so rep iterations can't be folded/CSE'd
    int off = 0;
    asm volatile("" : "+v"(off));

    float a1[TR], a2[TR];

#pragma unroll 1
    for (int rep = 0; rep < REP; ++rep) {
        float z0 = 0.f;
        asm volatile("" : "+v"(z0));          // opaque per-rep zero
#pragma unroll
        for (int r = 0; r < TR; ++r) { a1[r] = z0; a2[r] = z0; }

#pragma unroll 4
        for (int it = 0; it < iters; ++it) {
            const int j = it * BLOCK + tid + off;   // off==0, opaque
            float4 sv = sf[j];
            float w  = weights[j];
            float lw = log_weights[j];
            float cn = Kinv[0] * sv.x * sv.x;
            cn = fmaf(Kinv[1] * sv.y, sv.y, cn);
            cn = fmaf(Kinv[2] * sv.z, sv.z, cn);
            cn = fmaf(Kinv[3] * sv.w, sv.w, cn);
            float elw = __builtin_amdgcn_exp2f(fmaf(lw, LOG2E, cn));
            float ew  = __builtin_amdgcn_exp2f(fmaf(w,  LOG2E, cn));
#pragma unroll
            for (int r = 0; r < TR; ++r) {
                float t = fmaf(M0[r], sv.x, 0.f);
                t = fmaf(M1[r], sv.y, t);
                t = fmaf(M2[r], sv.z, t);
                t = fmaf(M3[r], sv.w, t);
                float e = __builtin_amdgcn_exp2f(t);
                a1[r] = fmaf(e, elw, a1[r]);
                a2[r] = fmaf(e, ew,  a2[r]);
            }
        }

        // sink: every rep's result observed -> no dead-code elimination
#pragma unroll
        for (int r = 0; r < TR; ++r)
            asm volatile("" :: "v"(a1[r]), "v"(a2[r]));
    }

    // ---- 64-lane butterfly per row (fixed order -> deterministic) ----
#pragma unroll
    for (int r = 0; r < TR; ++r) {
#pragma unroll
        for (int mask = 32; mask >= 1; mask >>= 1) {
            a1[r] += __shfl_xor(a1[r], mask, 64);
            a2[r] += __shfl_xor(a2[r], mask, 64);
        }
    }

    // ---- cross-wave combine via small LDS, fixed order ----
    __shared__ float red[NW][2 * TR];
    if (lane == 0) {
#pragma unroll
        for (int r = 0; r < TR; ++r) {
            red[wv][r]      = a1[r];
            red[wv][TR + r] = a2[r];
        }
    }
    __syncthreads();
    if (tid < TR) {
        float s1 = 0.f, s2 = 0.f;
#pragma unroll
        for (int w = 0; w < NW; ++w) {
            s1 += red[w][tid];
            s2 += red[w][TR + tid];
        }
        out[rowBase + tid] =
            (__builtin_amdgcn_logf(s2) - __builtin_amdgcn_logf(s1)) * LN2;
    }
}

extern "C" void kernel_launch(void* const* d_in, const int* in_sizes, int n_in,
                              void* d_out, int out_size, void* d_ws, size_t ws_size,
                              hipStream_t stream)
{
    const float* particles   = (const float*)d_in[0];
    const float* samples     = (const float*)d_in[1];
    const float* weights     = (const float*)d_in[2];
    const float* log_weights = (const float*)d_in[3];
    const float* A           = (const float*)d_in[4];
    const float* B           = (const float*)d_in[5];
    const float* log_sigma   = (const float*)d_in[6];

    const int P = in_sizes[2];  // weights is (P,)

    constexpr int BLOCK = 256, TR = 8, REP = 8;

    fused_diag<TR, BLOCK, REP><<<P / TR, BLOCK, 0, stream>>>(
        particles, samples, weights, log_weights, A, B, log_sigma,
        (float*)d_out, P);
}